// Round 6
// baseline (202.135 us; speedup 1.0000x reference)
//
#include <hip/hip_runtime.h>
#include <hip/hip_fp16.h>
#include <math.h>

typedef _Float16 half8 __attribute__((ext_vector_type(8)));
typedef float floatx4 __attribute__((ext_vector_type(4)));

#define BB 32
#define SS 48
#define LL 64
#define FF 256

// ---- prep: swizzle W1 (256x256 fp32) into fp16 hi/lo MFMA-B fragment order ----
// layout: flat = ((kt*16 + nt)*64 + lane)*8 + j
//   element = W1[kt*32 + (lane>>4)*8 + j][nt*16 + (lane&15)]
__global__ __launch_bounds__(256) void prep_w(const float* __restrict__ W1,
                                              _Float16* __restrict__ whi,
                                              _Float16* __restrict__ wlo) {
    int idx = blockIdx.x * 256 + threadIdx.x;
    int j    = idx & 7;
    int lane = (idx >> 3) & 63;
    int nt   = (idx >> 9) & 15;
    int kt   = idx >> 13;
    int k = kt * 32 + ((lane >> 4) & 3) * 8 + j;
    int n = nt * 16 + (lane & 15);
    float x = W1[k * FF + n];
    _Float16 hi = (_Float16)x;
    _Float16 lo = (_Float16)(x - (float)hi);
    whi[idx] = hi;
    wlo[idx] = lo;
}

// ---- main fused kernel: one block per TWO (b,s) groups: M=128 rows ----
// A staged per K-half in LDS (fp16 hi/lo, frag order); B JIT per kt from L2.
__global__ __launch_bounds__(256, 2) void ida_mfma(
    const float* __restrict__ features,
    const float* __restrict__ src_locs,
    const float* __restrict__ tar_locs,
    const _Float16* __restrict__ whi,
    const _Float16* __restrict__ wlo,
    const float* __restrict__ b1,
    const float* __restrict__ W2,
    const float* __restrict__ b2,
    float* __restrict__ out)
{
    __shared__ _Float16 Ahi[16384];   // 32 KiB: [(mtg*4+ktl)*64 + lane]*8
    __shared__ _Float16 Alo[16384];   // 32 KiB

    const int t    = threadIdx.x;
    const int w    = t >> 6;          // wave 0..3 -> owns cols 64w..64w+63, all 128 rows
    const int lane = t & 63;
    const int quad = lane >> 4;
    const int l16  = lane & 15;
    const int blk  = blockIdx.x;      // 0..767, rows blk*128..blk*128+127 of (98304,256)

    const float* Xg = features + (size_t)blk * 128 * FF;

    floatx4 acc[8][4] = {};           // [mt 0..7][nt local 0..3]

    for (int kh = 0; kh < 2; ++kh) {
        __syncthreads();              // previous half's A reads complete
        // stage: wave w converts rows 32w..32w+31, cols kh*128..kh*128+127
        #pragma unroll
        for (int rg = 0; rg < 2; ++rg) {
            const int mtg = 2 * w + rg;
            #pragma unroll
            for (int ktl = 0; ktl < 4; ++ktl) {
                const float4* p = (const float4*)(Xg + (mtg * 16 + l16) * FF + kh * 128 + ktl * 32 + quad * 8);
                float4 x0 = p[0], x1 = p[1];
                float xs[8] = {x0.x, x0.y, x0.z, x0.w, x1.x, x1.y, x1.z, x1.w};
                half8 hi, lo;
                #pragma unroll
                for (int j = 0; j < 8; ++j) {
                    _Float16 h = (_Float16)xs[j];
                    hi[j] = h;
                    lo[j] = (_Float16)(xs[j] - (float)h);
                }
                *((half8*)&Ahi[((mtg * 4 + ktl) * 64 + lane) * 8]) = hi;
                *((half8*)&Alo[((mtg * 4 + ktl) * 64 + lane) * 8]) = lo;
            }
        }
        __syncthreads();

        // compute this K-half
        #pragma unroll
        for (int ktl = 0; ktl < 4; ++ktl) {
            const int kt = kh * 4 + ktl;
            half8 bh[4], bl[4];
            #pragma unroll
            for (int nt = 0; nt < 4; ++nt) {
                size_t off = ((size_t)(kt * 16 + w * 4 + nt) * 64 + lane) * 8;
                bh[nt] = *((const half8*)(whi + off));
                bl[nt] = *((const half8*)(wlo + off));
            }
            #pragma unroll
            for (int mt = 0; mt < 8; ++mt) {
                half8 ahi = *((half8*)&Ahi[((mt * 4 + ktl) * 64 + lane) * 8]);
                half8 alo = *((half8*)&Alo[((mt * 4 + ktl) * 64 + lane) * 8]);
                #pragma unroll
                for (int nt = 0; nt < 4; ++nt) {
                    acc[mt][nt] = __builtin_amdgcn_mfma_f32_16x16x32_f16(ahi, bh[nt], acc[mt][nt], 0, 0, 0);
                    acc[mt][nt] = __builtin_amdgcn_mfma_f32_16x16x32_f16(ahi, bl[nt], acc[mt][nt], 0, 0, 0);
                    acc[mt][nt] = __builtin_amdgcn_mfma_f32_16x16x32_f16(alo, bh[nt], acc[mt][nt], 0, 0, 0);
                }
            }
        }
    }
    __syncthreads();                  // A buffers dead; alias epilogue scratch into Ahi

    float* SP   = (float*)Ahi;        // [128 rows][4 waves]  (2 KiB)
    float* wbuf = SP + 512;           // [128] softmax weights
    float* red  = wbuf + 128;         // [4 waves][256]       (4 KiB)

    // ---- layer-2: per-row partial over this wave's 64 cols ----
    float b1v[4], w2v[4];
    #pragma unroll
    for (int nt = 0; nt < 4; ++nt) {
        int n = (w * 4 + nt) * 16 + l16;
        b1v[nt] = b1[n];
        w2v[nt] = W2[n];
    }
    #pragma unroll
    for (int mt = 0; mt < 8; ++mt) {
        #pragma unroll
        for (int r = 0; r < 4; ++r) {
            float p = 0.f;
            #pragma unroll
            for (int nt = 0; nt < 4; ++nt) {
                float h = fmaxf(acc[mt][nt][r] + b1v[nt], 0.f);
                p = fmaf(h, w2v[nt], p);
            }
            p += __shfl_xor(p, 1);
            p += __shfl_xor(p, 2);
            p += __shfl_xor(p, 4);
            p += __shfl_xor(p, 8);
            if (l16 == 0) SP[(mt * 16 + quad * 4 + r) * 4 + w] = p;
        }
    }
    __syncthreads();

    // ---- inverse-distance softmax: waves 0,1 handle the two (b,s) groups ----
    if (t < 128) {
        const int g   = t >> 6;       // group 0/1 within block == wave id
        const int l   = t & 63;
        const int bsg = blk * 2 + g;
        const int b   = bsg / SS;
        float s = SP[4 * t] + SP[4 * t + 1] + SP[4 * t + 2] + SP[4 * t + 3] + b2[0];
        float score = fmaxf(s, 0.f);
        float dx = src_locs[(b * LL + l) * 2 + 0] - tar_locs[b * 2 + 0];
        float dy = src_locs[(b * LL + l) * 2 + 1] - tar_locs[b * 2 + 1];
        float inv = 1.0f / sqrtf(dx * dx + dy * dy);
        float logit = score * inv;
        float m = logit;
        #pragma unroll
        for (int o = 32; o > 0; o >>= 1) m = fmaxf(m, __shfl_xor(m, o));
        float e = __expf(logit - m);
        float se = e;
        #pragma unroll
        for (int o = 32; o > 0; o >>= 1) se += __shfl_xor(se, o);
        wbuf[t] = e / se;
    }
    __syncthreads();

    // ---- weighted sum: wave w accumulates rows 32w..32w+31 (within one group) ----
    {
        const float4* Xg4 = (const float4*)Xg;
        floatx4 o = {0.f, 0.f, 0.f, 0.f};
        #pragma unroll
        for (int lr = 0; lr < 32; ++lr) {
            int r = 32 * w + lr;              // rows 0..63 -> group 0, 64..127 -> group 1
            float wl = wbuf[r];
            float4 x = Xg4[r * 64 + lane];    // coalesced
            o[0] = fmaf(x.x, wl, o[0]);
            o[1] = fmaf(x.y, wl, o[1]);
            o[2] = fmaf(x.z, wl, o[2]);
            o[3] = fmaf(x.w, wl, o[3]);
        }
        #pragma unroll
        for (int j = 0; j < 4; ++j)
            red[w * FF + lane * 4 + j] = o[j];
    }
    __syncthreads();
    {
        float o0 = red[0 * FF + t] + red[1 * FF + t];   // group 0 (waves 0+1)
        float o1 = red[2 * FF + t] + red[3 * FF + t];   // group 1 (waves 2+3)
        out[(size_t)(blk * 2 + 0) * FF + t] = o0;
        out[(size_t)(blk * 2 + 1) * FF + t] = o1;
    }
}

extern "C" void kernel_launch(void* const* d_in, const int* in_sizes, int n_in,
                              void* d_out, int out_size, void* d_ws, size_t ws_size,
                              hipStream_t stream) {
    const float* features = (const float*)d_in[0];
    const float* src_locs = (const float*)d_in[1];
    const float* tar_locs = (const float*)d_in[2];
    const float* W1       = (const float*)d_in[3];
    const float* b1       = (const float*)d_in[4];
    const float* W2       = (const float*)d_in[5];
    const float* b2       = (const float*)d_in[6];
    float* out = (float*)d_out;

    _Float16* whi = (_Float16*)d_ws;               // 128 KiB
    _Float16* wlo = whi + FF * FF;                 // 128 KiB

    prep_w<<<dim3(FF * FF / 256), dim3(256), 0, stream>>>(W1, whi, wlo);
    ida_mfma<<<dim3(BB * SS / 2), dim3(256), 0, stream>>>(
        features, src_locs, tar_locs, whi, wlo, b1, W2, b2, out);
}

// Round 9
// 191.705 us; speedup vs baseline: 1.0544x; 1.0544x over previous
//
#include <hip/hip_runtime.h>
#include <hip/hip_fp16.h>
#include <math.h>

typedef _Float16 half8 __attribute__((ext_vector_type(8)));
typedef float floatx4 __attribute__((ext_vector_type(4)));

#define BB 32
#define SS 48
#define LL 64
#define FF 256

// ---- prep: W1 (256x256 fp32) -> fp16 hi/lo in MFMA-B fragment order ----
// frag layout: flat = ((kt*16 + nt)*64 + lane)*8 + j
//   element    = W1[kt*32 + (lane>>4)*8 + j][nt*16 + (lane&15)]
__global__ __launch_bounds__(256) void prep_w(const float* __restrict__ W1,
                                              _Float16* __restrict__ whi,
                                              _Float16* __restrict__ wlo) {
    int idx = blockIdx.x * 256 + threadIdx.x;  // = k*256 + n
    float x = W1[idx];
    int k = idx >> 8, n = idx & 255;
    int kt = k >> 5, quad = (k >> 3) & 3, j = k & 7;
    int nt = n >> 4, l16 = n & 15;
    int lane = quad * 16 + l16;
    size_t off = ((size_t)(kt * 16 + nt) * 64 + lane) * 8 + j;
    _Float16 hi = (_Float16)x;
    whi[off] = hi;
    wlo[off] = (_Float16)(x - (float)hi);
}

// ---- kernel A: GEMM + layer-2 + inv-dist logits only (R2-proven structure) ----
// wave w owns cols 64w..64w+63; A staged per K-half in LDS; B JIT per kt (16 regs).
__global__ __launch_bounds__(256, 4) void ida_scores(
    const float* __restrict__ features,
    const float* __restrict__ src_locs,
    const float* __restrict__ tar_locs,
    const _Float16* __restrict__ whi,
    const _Float16* __restrict__ wlo,
    const float* __restrict__ b1,
    const float* __restrict__ W2,
    const float* __restrict__ b2,
    float* __restrict__ logits)
{
    __shared__ _Float16 Ahi[8192];   // 16 KiB: [(w*4+ktl)*64 + lane]*8
    __shared__ _Float16 Alo[8192];   // 16 KiB
    __shared__ float SP[LL * 4];     // layer-2 partials [row][wave]

    const int t    = threadIdx.x;
    const int w    = t >> 6;
    const int lane = t & 63;
    const int quad = lane >> 4;
    const int l16  = lane & 15;
    const int bs   = blockIdx.x;
    const int b    = bs / SS;

    const float* Xg = features + (size_t)bs * (LL * FF);

    floatx4 acc[4][4] = {};          // [mt][nt_local] -> 64 AGPRs

    for (int kh = 0; kh < 2; ++kh) {
        __syncthreads();
        // stage+convert: wave w stages rows 16w..16w+15 for 4 ktl
        for (int ktl = 0; ktl < 4; ++ktl) {
            int kt = kh * 4 + ktl;
            const float4* p = (const float4*)(Xg + (w * 16 + l16) * FF + kt * 32 + quad * 8);
            float4 x0 = p[0], x1 = p[1];
            float xs[8] = {x0.x, x0.y, x0.z, x0.w, x1.x, x1.y, x1.z, x1.w};
            half8 hi, lo;
            #pragma unroll
            for (int j = 0; j < 8; ++j) {
                _Float16 h = (_Float16)xs[j];
                hi[j] = h;
                lo[j] = (_Float16)(xs[j] - (float)h);
            }
            *((half8*)&Ahi[((w * 4 + ktl) * 64 + lane) * 8]) = hi;
            *((half8*)&Alo[((w * 4 + ktl) * 64 + lane) * 8]) = lo;
        }
        __syncthreads();

        // compute this K-half, B JIT per kt (R2-proven)
        #pragma unroll
        for (int ktl = 0; ktl < 4; ++ktl) {
            const int kt = kh * 4 + ktl;
            half8 bh[4], bl[4];
            #pragma unroll
            for (int nt = 0; nt < 4; ++nt) {
                size_t off = ((size_t)(kt * 16 + w * 4 + nt) * 64 + lane) * 8;
                bh[nt] = *((const half8*)(whi + off));
                bl[nt] = *((const half8*)(wlo + off));
            }
            #pragma unroll
            for (int mt = 0; mt < 4; ++mt) {
                half8 ahi = *((half8*)&Ahi[((mt * 4 + ktl) * 64 + lane) * 8]);
                half8 alo = *((half8*)&Alo[((mt * 4 + ktl) * 64 + lane) * 8]);
                #pragma unroll
                for (int nt = 0; nt < 4; ++nt) {
                    acc[mt][nt] = __builtin_amdgcn_mfma_f32_16x16x32_f16(ahi, bh[nt], acc[mt][nt], 0, 0, 0);
                    acc[mt][nt] = __builtin_amdgcn_mfma_f32_16x16x32_f16(ahi, bl[nt], acc[mt][nt], 0, 0, 0);
                    acc[mt][nt] = __builtin_amdgcn_mfma_f32_16x16x32_f16(alo, bh[nt], acc[mt][nt], 0, 0, 0);
                }
            }
        }
    }

    // ---- layer-2 fold (R5-proven) ----
    float b1v[4], w2v[4];
    #pragma unroll
    for (int nt = 0; nt < 4; ++nt) {
        int n = (w * 4 + nt) * 16 + l16;
        b1v[nt] = b1[n];
        w2v[nt] = W2[n];
    }
    #pragma unroll
    for (int mt = 0; mt < 4; ++mt) {
        #pragma unroll
        for (int r = 0; r < 4; ++r) {
            float p = 0.f;
            #pragma unroll
            for (int nt = 0; nt < 4; ++nt) {
                float h = fmaxf(acc[mt][nt][r] + b1v[nt], 0.f);
                p = fmaf(h, w2v[nt], p);
            }
            p += __shfl_xor(p, 1);
            p += __shfl_xor(p, 2);
            p += __shfl_xor(p, 4);
            p += __shfl_xor(p, 8);
            if (l16 == 0) SP[(mt * 16 + quad * 4 + r) * 4 + w] = p;
        }
    }
    __syncthreads();

    // ---- logits: relu(score + b2) * inv_dist, written to ws ----
    if (t < LL) {
        float s = SP[4 * t] + SP[4 * t + 1] + SP[4 * t + 2] + SP[4 * t + 3] + b2[0];
        float score = fmaxf(s, 0.f);
        float dx = src_locs[(b * LL + t) * 2 + 0] - tar_locs[b * 2 + 0];
        float dy = src_locs[(b * LL + t) * 2 + 1] - tar_locs[b * 2 + 1];
        float inv = 1.0f / sqrtf(dx * dx + dy * dy);
        logits[(size_t)bs * LL + t] = score * inv;
    }
}

// ---- kernel B: softmax over L + weighted feature sum (R5-proven epilogue) ----
__global__ __launch_bounds__(256) void ida_finalize(
    const float* __restrict__ features,
    const float* __restrict__ logits,
    float* __restrict__ out)
{
    __shared__ float wbuf[LL];
    __shared__ float red[4 * FF];

    const int t    = threadIdx.x;
    const int w    = t >> 6;
    const int lane = t & 63;
    const int bs   = blockIdx.x;

    const float* Xg = features + (size_t)bs * (LL * FF);

    if (t < LL) {
        float logit = logits[(size_t)bs * LL + t];
        float m = logit;
        #pragma unroll
        for (int o = 32; o > 0; o >>= 1) m = fmaxf(m, __shfl_xor(m, o));
        float e = __expf(logit - m);
        float se = e;
        #pragma unroll
        for (int o = 32; o > 0; o >>= 1) se += __shfl_xor(se, o);
        wbuf[t] = e / se;
    }
    __syncthreads();

    {
        const float4* Xg4 = (const float4*)Xg;
        floatx4 o = {0.f, 0.f, 0.f, 0.f};
        #pragma unroll
        for (int lr = 0; lr < 16; ++lr) {
            int l = w * 16 + lr;
            float wl = wbuf[l];
            float4 x = Xg4[l * 64 + lane];
            o[0] = fmaf(x.x, wl, o[0]);
            o[1] = fmaf(x.y, wl, o[1]);
            o[2] = fmaf(x.z, wl, o[2]);
            o[3] = fmaf(x.w, wl, o[3]);
        }
        #pragma unroll
        for (int j = 0; j < 4; ++j)
            red[w * FF + lane * 4 + j] = o[j];
    }
    __syncthreads();
    {
        float o = red[0 * FF + t] + red[1 * FF + t] + red[2 * FF + t] + red[3 * FF + t];
        out[(size_t)bs * FF + t] = o;
    }
}

extern "C" void kernel_launch(void* const* d_in, const int* in_sizes, int n_in,
                              void* d_out, int out_size, void* d_ws, size_t ws_size,
                              hipStream_t stream) {
    const float* features = (const float*)d_in[0];
    const float* src_locs = (const float*)d_in[1];
    const float* tar_locs = (const float*)d_in[2];
    const float* W1       = (const float*)d_in[3];
    const float* b1       = (const float*)d_in[4];
    const float* W2       = (const float*)d_in[5];
    const float* b2       = (const float*)d_in[6];
    float* out = (float*)d_out;

    _Float16* whi  = (_Float16*)d_ws;              // 128 KiB
    _Float16* wlo  = whi + FF * FF;                // 128 KiB
    float* logits  = (float*)(wlo + FF * FF);      // 384 KiB (BB*SS*LL floats)

    prep_w<<<dim3(FF * FF / 256), dim3(256), 0, stream>>>(W1, whi, wlo);
    ida_scores<<<dim3(BB * SS), dim3(256), 0, stream>>>(
        features, src_locs, tar_locs, whi, wlo, b1, W2, b2, logits);
    ida_finalize<<<dim3(BB * SS), dim3(256), 0, stream>>>(features, logits, out);
}

// Round 10
// 182.339 us; speedup vs baseline: 1.1086x; 1.0514x over previous
//
#include <hip/hip_runtime.h>
#include <hip/hip_fp16.h>
#include <math.h>

typedef _Float16 half8 __attribute__((ext_vector_type(8)));
typedef float floatx4 __attribute__((ext_vector_type(4)));

#define BB 32
#define SS 48
#define LL 64
#define FF 256

// ---- prep (R2-proven): W1 -> fp16 hi/lo MFMA-B fragment order ----
// gather-read, coalesced-write. frag layout:
//   flat = ((kt*16 + nt)*64 + lane)*8 + j ; element = W1[kt*32+(lane>>4)*8+j][nt*16+(lane&15)]
__global__ __launch_bounds__(256) void prep_w(const float* __restrict__ W1,
                                              _Float16* __restrict__ whi,
                                              _Float16* __restrict__ wlo) {
    int idx = blockIdx.x * 256 + threadIdx.x;
    int j    = idx & 7;
    int lane = (idx >> 3) & 63;
    int nt   = (idx >> 9) & 15;
    int kt   = idx >> 13;
    int k = kt * 32 + ((lane >> 4) & 3) * 8 + j;
    int n = nt * 16 + (lane & 15);
    float x = W1[k * FF + n];
    _Float16 hi = (_Float16)x;
    _Float16 lo = (_Float16)(x - (float)hi);
    whi[idx] = hi;
    wlo[idx] = lo;
}

// ---- fused kernel: R5 base, two halves peeled straight-line ----
// half0: B0 preloaded, A0 staged; during half0 compute, A1 raw loads in flight;
// B1 refilled after half0 compute (hides under stage1, which has no global wait).
__global__ __launch_bounds__(256, 2) void ida_mfma(
    const float* __restrict__ features,
    const float* __restrict__ src_locs,
    const float* __restrict__ tar_locs,
    const _Float16* __restrict__ whi,
    const _Float16* __restrict__ wlo,
    const float* __restrict__ b1,
    const float* __restrict__ W2,
    const float* __restrict__ b2,
    float* __restrict__ out)
{
    __shared__ _Float16 Ahi[8192];   // 16 KiB: [(w*4+ktl)*64 + lane]*8
    __shared__ _Float16 Alo[8192];   // 16 KiB
    __shared__ float SP[LL * 4];     // layer-2 partials [row][wave]
    __shared__ float wbuf[LL];       // softmax weights
    __shared__ float red[4 * FF];    // weighted-sum cross-wave reduce

    const int t    = threadIdx.x;
    const int w    = t >> 6;         // wave 0..3 -> owns cols 64w..64w+63
    const int lane = t & 63;
    const int quad = lane >> 4;
    const int l16  = lane & 15;
    const int bs   = blockIdx.x;
    const int b    = bs / SS;

    const float* Xg = features + (size_t)bs * (LL * FF);

    floatx4 acc[4][4] = {};          // [mt][nt_local] -> 64 AGPRs
    half8 bh[4][4], bl[4][4];        // B fragments for current half: 128 VGPRs

    // ---- preload B for half 0 ----
    #pragma unroll
    for (int ktl = 0; ktl < 4; ++ktl)
        #pragma unroll
        for (int nt = 0; nt < 4; ++nt) {
            size_t off = ((size_t)(ktl * 16 + w * 4 + nt) * 64 + lane) * 8;
            bh[ktl][nt] = *((const half8*)(whi + off));
            bl[ktl][nt] = *((const half8*)(wlo + off));
        }

    // ---- stage half 0 (A0: global load + cvt + ds_write) ----
    for (int ktl = 0; ktl < 4; ++ktl) {
        const float4* p = (const float4*)(Xg + (w * 16 + l16) * FF + ktl * 32 + quad * 8);
        float4 x0 = p[0], x1 = p[1];
        float xs[8] = {x0.x, x0.y, x0.z, x0.w, x1.x, x1.y, x1.z, x1.w};
        half8 hi, lo;
        #pragma unroll
        for (int j = 0; j < 8; ++j) {
            _Float16 h = (_Float16)xs[j];
            hi[j] = h;
            lo[j] = (_Float16)(xs[j] - (float)h);
        }
        *((half8*)&Ahi[((w * 4 + ktl) * 64 + lane) * 8]) = hi;
        *((half8*)&Alo[((w * 4 + ktl) * 64 + lane) * 8]) = lo;
    }

    // ---- issue A1 raw loads now; latency hides under half-0 compute ----
    float4 a1raw[8];
    #pragma unroll
    for (int ktl = 0; ktl < 4; ++ktl) {
        const float4* p = (const float4*)(Xg + (w * 16 + l16) * FF + (4 + ktl) * 32 + quad * 8);
        a1raw[2 * ktl + 0] = p[0];
        a1raw[2 * ktl + 1] = p[1];
    }

    __syncthreads();

    // ---- compute half 0 ----
    #pragma unroll
    for (int ktl = 0; ktl < 4; ++ktl) {
        #pragma unroll
        for (int mt = 0; mt < 4; ++mt) {
            half8 ahi = *((half8*)&Ahi[((mt * 4 + ktl) * 64 + lane) * 8]);
            half8 alo = *((half8*)&Alo[((mt * 4 + ktl) * 64 + lane) * 8]);
            #pragma unroll
            for (int nt = 0; nt < 4; ++nt) {
                acc[mt][nt] = __builtin_amdgcn_mfma_f32_16x16x32_f16(ahi, bh[ktl][nt], acc[mt][nt], 0, 0, 0);
                acc[mt][nt] = __builtin_amdgcn_mfma_f32_16x16x32_f16(ahi, bl[ktl][nt], acc[mt][nt], 0, 0, 0);
                acc[mt][nt] = __builtin_amdgcn_mfma_f32_16x16x32_f16(alo, bh[ktl][nt], acc[mt][nt], 0, 0, 0);
            }
        }
    }

    // ---- refill B for half 1 (R5-proven placement; hides under stage1) ----
    #pragma unroll
    for (int ktl = 0; ktl < 4; ++ktl)
        #pragma unroll
        for (int nt = 0; nt < 4; ++nt) {
            size_t off = ((size_t)((4 + ktl) * 16 + w * 4 + nt) * 64 + lane) * 8;
            bh[ktl][nt] = *((const half8*)(whi + off));
            bl[ktl][nt] = *((const half8*)(wlo + off));
        }

    __syncthreads();   // half-0 LDS reads complete before overwrite

    // ---- stage half 1 (cvt + ds_write only; a1raw already long in flight) ----
    for (int ktl = 0; ktl < 4; ++ktl) {
        float4 x0 = a1raw[2 * ktl + 0], x1 = a1raw[2 * ktl + 1];
        float xs[8] = {x0.x, x0.y, x0.z, x0.w, x1.x, x1.y, x1.z, x1.w};
        half8 hi, lo;
        #pragma unroll
        for (int j = 0; j < 8; ++j) {
            _Float16 h = (_Float16)xs[j];
            hi[j] = h;
            lo[j] = (_Float16)(xs[j] - (float)h);
        }
        *((half8*)&Ahi[((w * 4 + ktl) * 64 + lane) * 8]) = hi;
        *((half8*)&Alo[((w * 4 + ktl) * 64 + lane) * 8]) = lo;
    }
    __syncthreads();

    // ---- compute half 1 ----
    #pragma unroll
    for (int ktl = 0; ktl < 4; ++ktl) {
        #pragma unroll
        for (int mt = 0; mt < 4; ++mt) {
            half8 ahi = *((half8*)&Ahi[((mt * 4 + ktl) * 64 + lane) * 8]);
            half8 alo = *((half8*)&Alo[((mt * 4 + ktl) * 64 + lane) * 8]);
            #pragma unroll
            for (int nt = 0; nt < 4; ++nt) {
                acc[mt][nt] = __builtin_amdgcn_mfma_f32_16x16x32_f16(ahi, bh[ktl][nt], acc[mt][nt], 0, 0, 0);
                acc[mt][nt] = __builtin_amdgcn_mfma_f32_16x16x32_f16(ahi, bl[ktl][nt], acc[mt][nt], 0, 0, 0);
                acc[mt][nt] = __builtin_amdgcn_mfma_f32_16x16x32_f16(alo, bh[ktl][nt], acc[mt][nt], 0, 0, 0);
            }
        }
    }

    // ---- layer-2 fold (R5-verbatim) ----
    float b1v[4], w2v[4];
    #pragma unroll
    for (int nt = 0; nt < 4; ++nt) {
        int n = (w * 4 + nt) * 16 + l16;
        b1v[nt] = b1[n];
        w2v[nt] = W2[n];
    }
    #pragma unroll
    for (int mt = 0; mt < 4; ++mt) {
        #pragma unroll
        for (int r = 0; r < 4; ++r) {
            float p = 0.f;
            #pragma unroll
            for (int nt = 0; nt < 4; ++nt) {
                float h = fmaxf(acc[mt][nt][r] + b1v[nt], 0.f);
                p = fmaf(h, w2v[nt], p);
            }
            p += __shfl_xor(p, 1);
            p += __shfl_xor(p, 2);
            p += __shfl_xor(p, 4);
            p += __shfl_xor(p, 8);
            if (l16 == 0) SP[(mt * 16 + quad * 4 + r) * 4 + w] = p;
        }
    }
    __syncthreads();

    // ---- inverse-distance softmax over L=64 (wave 0; R5-verbatim) ----
    if (t < LL) {
        float s = SP[4 * t] + SP[4 * t + 1] + SP[4 * t + 2] + SP[4 * t + 3] + b2[0];
        float score = fmaxf(s, 0.f);
        float dx = src_locs[(b * LL + t) * 2 + 0] - tar_locs[b * 2 + 0];
        float dy = src_locs[(b * LL + t) * 2 + 1] - tar_locs[b * 2 + 1];
        float inv = 1.0f / sqrtf(dx * dx + dy * dy);
        float logit = score * inv;
        float m = logit;
        #pragma unroll
        for (int o = 32; o > 0; o >>= 1) m = fmaxf(m, __shfl_xor(m, o));
        float e = __expf(logit - m);
        float se = e;
        #pragma unroll
        for (int o = 32; o > 0; o >>= 1) se += __shfl_xor(se, o);
        wbuf[t] = e / se;
    }
    __syncthreads();

    // ---- weighted sum over stations (R5-verbatim) ----
    {
        const float4* Xg4 = (const float4*)Xg;
        floatx4 o = {0.f, 0.f, 0.f, 0.f};
        #pragma unroll
        for (int lr = 0; lr < 16; ++lr) {
            int l = w * 16 + lr;
            float wl = wbuf[l];
            float4 x = Xg4[l * 64 + lane];
            o[0] = fmaf(x.x, wl, o[0]);
            o[1] = fmaf(x.y, wl, o[1]);
            o[2] = fmaf(x.z, wl, o[2]);
            o[3] = fmaf(x.w, wl, o[3]);
        }
        #pragma unroll
        for (int j = 0; j < 4; ++j)
            red[w * FF + lane * 4 + j] = o[j];
    }
    __syncthreads();
    {
        float o = red[0 * FF + t] + red[1 * FF + t] + red[2 * FF + t] + red[3 * FF + t];
        out[(size_t)bs * FF + t] = o;
    }
}

extern "C" void kernel_launch(void* const* d_in, const int* in_sizes, int n_in,
                              void* d_out, int out_size, void* d_ws, size_t ws_size,
                              hipStream_t stream) {
    const float* features = (const float*)d_in[0];
    const float* src_locs = (const float*)d_in[1];
    const float* tar_locs = (const float*)d_in[2];
    const float* W1       = (const float*)d_in[3];
    const float* b1       = (const float*)d_in[4];
    const float* W2       = (const float*)d_in[5];
    const float* b2       = (const float*)d_in[6];
    float* out = (float*)d_out;

    _Float16* whi = (_Float16*)d_ws;               // 128 KiB
    _Float16* wlo = whi + FF * FF;                 // 128 KiB

    prep_w<<<dim3(FF * FF / 256), dim3(256), 0, stream>>>(W1, whi, wlo);
    ida_mfma<<<dim3(BB * SS), dim3(256), 0, stream>>>(
        features, src_locs, tar_locs, whi, wlo, b1, W2, b2, out);
}